// Round 1
// baseline (1170.673 us; speedup 1.0000x reference)
//
#include <hip/hip_runtime.h>
#include <math.h>

#define BB 16
#define PIX 4096      // 64*64
#define NPIX 65536    // B*H*W
#define HID 12
#define LIFT 256
#define OUT_CH 640
#define EPS 1e-5f

__device__ __forceinline__ float gelu_f(float x) {
    return 0.5f * x * (1.0f + erff(x * 0.70710678118654752f));
}

// ---------------- BN2d stats over all of x ----------------
__global__ __launch_bounds__(256) void k_bn_stats(const float* __restrict__ x,
                                                  float* __restrict__ stats) {
    __shared__ float s1[256], s2[256];
    float a = 0.f, b = 0.f;
    for (int i = threadIdx.x; i < NPIX; i += 256) { float v = x[i]; a += v; b += v * v; }
    s1[threadIdx.x] = a; s2[threadIdx.x] = b;
    __syncthreads();
    for (int off = 128; off > 0; off >>= 1) {
        if (threadIdx.x < off) { s1[threadIdx.x] += s1[threadIdx.x + off];
                                 s2[threadIdx.x] += s2[threadIdx.x + off]; }
        __syncthreads();
    }
    if (threadIdx.x == 0) {
        float m = s1[0] / (float)NPIX;
        float var = s2[0] / (float)NPIX - m * m;
        stats[0] = m;
        stats[1] = rsqrtf(var + EPS);
    }
}

// ---------------- condition BN1d + branch MLP ----------------
__global__ __launch_bounds__(64) void k_branch(const float* __restrict__ cond,
                                               const float* __restrict__ g1, const float* __restrict__ b1,
                                               const float* __restrict__ w1, const float* __restrict__ bb1,
                                               const float* __restrict__ w2, const float* __restrict__ bb2,
                                               const float* __restrict__ w3, const float* __restrict__ bb3,
                                               float* __restrict__ br_out) {
    __shared__ float cm[2], cistd[2];
    int t = threadIdx.x;
    if (t < 2) {
        float s = 0.f;
        for (int i = 0; i < 16; i++) s += cond[i * 2 + t];
        float m = s / 16.f;
        float v = 0.f;
        for (int i = 0; i < 16; i++) { float d = cond[i * 2 + t] - m; v += d * d; }
        v /= 16.f;
        cm[t] = m; cistd[t] = rsqrtf(v + EPS);
    }
    __syncthreads();
    if (t < 16) {
        float c0 = (cond[t * 2 + 0] - cm[0]) * cistd[0] * g1[0] + b1[0];
        float c1 = (cond[t * 2 + 1] - cm[1]) * cistd[1] * g1[1] + b1[1];
        float h1[50], h2[50];
        for (int j = 0; j < 50; j++) h1[j] = tanhf(bb1[j] + c0 * w1[j] + c1 * w1[50 + j]);
        for (int j = 0; j < 50; j++) {
            float acc = bb2[j];
            for (int k = 0; k < 50; k++) acc += h1[k] * w2[k * 50 + j];
            h2[j] = tanhf(acc);
        }
        float acc = bb3[0];
        for (int k = 0; k < 50; k++) acc += h2[k] * w3[k];
        br_out[t] = tanhf(acc);
    }
}

// ---------------- lifting: xn -> gelu(xn*l1w+l1b) -> l2w ----------------
__global__ __launch_bounds__(256) void k_lift(const float* __restrict__ x, const float* __restrict__ stats,
                                              const float* __restrict__ g2, const float* __restrict__ b2,
                                              const float* __restrict__ l1w, const float* __restrict__ l1b,
                                              const float* __restrict__ l2w, const float* __restrict__ l2b,
                                              float* __restrict__ t0) {
    int p = blockIdx.x * 256 + threadIdx.x;
    float m = stats[0], istd = stats[1];
    float xn = (x[p] - m) * istd * g2[0] + b2[0];
    float acc[HID];
#pragma unroll
    for (int e = 0; e < HID; e++) acc[e] = l2b[e];
    for (int d = 0; d < LIFT; d++) {
        float g = gelu_f(xn * l1w[d] + l1b[d]);
#pragma unroll
        for (int e = 0; e < HID; e++) acc[e] += g * l2w[d * HID + e];
    }
    int b = p >> 12, px = p & 4095;
#pragma unroll
    for (int e = 0; e < HID; e++) t0[(b * HID + e) * PIX + px] = acc[e];
}

// ---------------- forward DFT along w (64 -> 16 modes) ----------------
// A[b][c][kw][h] complex
__global__ __launch_bounds__(256) void k_fwd_w(const float* __restrict__ tin, float2* __restrict__ A) {
    __shared__ float tl[64 * 65];
    __shared__ float ct[64], st[64];
    int bc = blockIdx.x;  // b*12+c
    int tid = threadIdx.x;
    if (tid < 64) { float s, c; sincospif(tid * (1.0f / 32.0f), &s, &c); ct[tid] = c; st[tid] = s; }
    const float* src = tin + bc * PIX;
    for (int i = tid; i < PIX; i += 256) {
        int h = i >> 6, w = i & 63;
        tl[h * 65 + w] = src[i];
    }
    __syncthreads();
    for (int o = tid; o < 1024; o += 256) {
        int kw = o >> 6, h = o & 63;
        float xr = 0.f, xi = 0.f;
        for (int w = 0; w < 64; w++) {
            int j = (kw * w) & 63;
            float v = tl[h * 65 + w];
            xr += v * ct[j];
            xi -= v * st[j];
        }
        A[(bc * 16 + kw) * 64 + h] = make_float2(xr, xi);
    }
}

// ---------------- forward DFT along h (64 -> 32 rows) + spectral multiply ----------------
// block = (b, kw); O[b][o][khidx][kw] complex; khidx 0..15 -> rows 0..15 (w1), 16..31 -> rows 48..63 (w2)
__global__ __launch_bounds__(384) void k_fwd_h_mul(const float2* __restrict__ A,
                                                   const float* __restrict__ w1r, const float* __restrict__ w1i,
                                                   const float* __restrict__ w2r, const float* __restrict__ w2i,
                                                   float2* __restrict__ O) {
    __shared__ float2 Al[12 * 64];
    __shared__ float2 Xl[12 * 32];
    __shared__ float ct[64], st[64];
    int b = blockIdx.x >> 4;
    int kw = blockIdx.x & 15;
    int tid = threadIdx.x;
    if (tid < 64) { float s, c; sincospif(tid * (1.0f / 32.0f), &s, &c); ct[tid] = c; st[tid] = s; }
    for (int i = tid; i < 12 * 64; i += 384) {
        int c = i >> 6, h = i & 63;
        Al[i] = A[((b * 12 + c) * 16 + kw) * 64 + h];
    }
    __syncthreads();
    {
        int c = tid >> 5, kh = tid & 31;
        int f = (kh < 16) ? kh : kh + 32;
        float xr = 0.f, xi = 0.f;
        for (int h = 0; h < 64; h++) {
            int j = (f * h) & 63;
            float2 a = Al[c * 64 + h];
            float cc = ct[j], ss = st[j];
            // (ar + i ai) * (cos - i sin)
            xr += a.x * cc + a.y * ss;
            xi += a.y * cc - a.x * ss;
        }
        Xl[c * 32 + kh] = make_float2(xr, xi);
    }
    __syncthreads();
    {
        int o = tid >> 5, kh = tid & 31;
        int khr = kh & 15;
        const float* wr = (kh < 16) ? w1r : w2r;
        const float* wi = (kh < 16) ? w1i : w2i;
        float orr = 0.f, oii = 0.f;
        for (int c = 0; c < 12; c++) {
            float2 xv = Xl[c * 32 + kh];
            int wIdx = ((c * 12 + o) * 16 + khr) * 16 + kw;
            float wrv = wr[wIdx], wiv = wi[wIdx];
            orr += xv.x * wrv - xv.y * wiv;
            oii += xv.x * wiv + xv.y * wrv;
        }
        O[((b * 12 + o) * 32 + kh) * 16 + kw] = make_float2(orr, oii);
    }
}

// ---------------- inverse: ifft along h (32 rows -> 64) then irfft along w (16 modes -> 64) ----------------
// block = (b, o)
__global__ __launch_bounds__(256) void k_inv(const float2* __restrict__ O, float* __restrict__ spec) {
    __shared__ float2 Ol[32 * 16];
    __shared__ float2 Yl[64 * 17];
    __shared__ float ct[64], st[64];
    int bo = blockIdx.x;
    int tid = threadIdx.x;
    if (tid < 64) { float s, c; sincospif(tid * (1.0f / 32.0f), &s, &c); ct[tid] = c; st[tid] = s; }
    for (int i = tid; i < 512; i += 256) Ol[i] = O[bo * 512 + i];
    __syncthreads();
    for (int oidx = tid; oidx < 1024; oidx += 256) {
        int kw = oidx >> 6, h = oidx & 63;
        float yr = 0.f, yi = 0.f;
        for (int kh = 0; kh < 32; kh++) {
            int f = (kh < 16) ? kh : kh + 32;
            int j = (f * h) & 63;
            float2 ov = Ol[kh * 16 + kw];
            float cc = ct[j], ss = st[j];
            // (or + i oi) * (cos + i sin)
            yr += ov.x * cc - ov.y * ss;
            yi += ov.x * ss + ov.y * cc;
        }
        Yl[h * 17 + kw] = make_float2(yr * (1.0f / 4096.0f), yi * (1.0f / 4096.0f));
    }
    __syncthreads();
    for (int i = tid; i < PIX; i += 256) {
        int h = i >> 6, w = i & 63;
        float acc = 0.f;
#pragma unroll
        for (int kw = 0; kw < 16; kw++) {
            int j = (kw * w) & 63;
            float2 yv = Yl[h * 17 + kw];
            float term = yv.x * ct[j] - yv.y * st[j];
            acc += (kw == 0) ? term : 2.0f * term;
        }
        spec[bo * PIX + i] = acc;
    }
}

// ---------------- spec + 1x1-conv skip + (gelu) ----------------
__global__ __launch_bounds__(256) void k_skip(const float* __restrict__ tin, const float* __restrict__ spec,
                                              const float* __restrict__ skw, const float* __restrict__ skb,
                                              float* __restrict__ tout, int apply_gelu) {
    int p = blockIdx.x * 256 + threadIdx.x;
    int b = p >> 12, px = p & 4095;
    float tr[12];
#pragma unroll
    for (int c = 0; c < 12; c++) tr[c] = tin[(b * 12 + c) * PIX + px];
#pragma unroll
    for (int o = 0; o < 12; o++) {
        float v = spec[(b * 12 + o) * PIX + px] + skb[o];
#pragma unroll
        for (int c = 0; c < 12; c++) v += tr[c] * skw[c * 12 + o];
        if (apply_gelu) v = gelu_f(v);
        tout[(b * 12 + o) * PIX + px] = v;
    }
}

// ---------------- projection 12->256->640, * branch, transposed write ----------------
// grid = (1024 pixel-tiles of 64, 5 e-tiles of 128), 256 threads
__global__ __launch_bounds__(256) void k_proj(const float* __restrict__ t, const float* __restrict__ p1w,
                                              const float* __restrict__ p1b, const float* __restrict__ p2w,
                                              const float* __restrict__ p2b, const float* __restrict__ brn,
                                              float* __restrict__ out) {
    __shared__ float ql[256 * 68];   // q transposed: [k][px], row pad 68
    __shared__ float wl[16 * 128];   // w chunk: [k][e]
    int pxt = blockIdx.x;
    int e0 = blockIdx.y * 128;
    int b = pxt >> 6;
    int h = pxt & 63;
    int tid = threadIdx.x;
    // phase A: compute q tile (64 px x 256 d), store transposed
    {
        int pxl = tid & 63;
        int dg = tid >> 6;  // 0..3
        int pimg = h * 64 + pxl;
        float tv[12];
#pragma unroll
        for (int c = 0; c < 12; c++) tv[c] = t[(b * 12 + c) * PIX + pimg];
        for (int dd = 0; dd < 64; dd++) {
            int d = dg * 64 + dd;
            float a = p1b[d];
#pragma unroll
            for (int c = 0; c < 12; c++) a += tv[c] * p1w[c * 256 + d];
            ql[d * 68 + pxl] = gelu_f(a);
        }
    }
    __syncthreads();
    float acc[4][8];
#pragma unroll
    for (int a = 0; a < 4; a++)
#pragma unroll
        for (int e = 0; e < 8; e++) acc[a][e] = 0.f;
    int ti = tid & 15, tj = tid >> 4;
    for (int kc = 0; kc < 16; kc++) {
        for (int i = tid; i < 16 * 128; i += 256) {
            int k = i >> 7, e = i & 127;
            wl[i] = p2w[(kc * 16 + k) * 640 + e0 + e];
        }
        __syncthreads();
#pragma unroll
        for (int k = 0; k < 16; k++) {
            int kk = kc * 16 + k;
            float4 qv = *(const float4*)&ql[kk * 68 + ti * 4];
            float4 wa = *(const float4*)&wl[k * 128 + tj * 8];
            float4 wb = *(const float4*)&wl[k * 128 + tj * 8 + 4];
            float qq[4] = {qv.x, qv.y, qv.z, qv.w};
            float ww[8] = {wa.x, wa.y, wa.z, wa.w, wb.x, wb.y, wb.z, wb.w};
#pragma unroll
            for (int a = 0; a < 4; a++)
#pragma unroll
                for (int e = 0; e < 8; e++) acc[a][e] += qq[a] * ww[e];
        }
        __syncthreads();
    }
    float brv = brn[b];
#pragma unroll
    for (int e = 0; e < 8; e++) {
        int ee = e0 + tj * 8 + e;
        float bias = p2b[ee];
        float4 v;
        v.x = (acc[0][e] + bias) * brv;
        v.y = (acc[1][e] + bias) * brv;
        v.z = (acc[2][e] + bias) * brv;
        v.w = (acc[3][e] + bias) * brv;
        *(float4*)&out[((b * 64 + h) * 640 + ee) * 64 + ti * 4] = v;
    }
}

extern "C" void kernel_launch(void* const* d_in, const int* in_sizes, int n_in,
                              void* d_out, int out_size, void* d_ws, size_t ws_size,
                              hipStream_t stream) {
    const float* x     = (const float*)d_in[0];
    const float* cond  = (const float*)d_in[1];
    const float* bn2_g = (const float*)d_in[2];
    const float* bn2_b = (const float*)d_in[3];
    const float* bn1_g = (const float*)d_in[4];
    const float* bn1_b = (const float*)d_in[5];
    const float* b_w1  = (const float*)d_in[6];
    const float* b_b1  = (const float*)d_in[7];
    const float* b_w2  = (const float*)d_in[8];
    const float* b_b2  = (const float*)d_in[9];
    const float* b_w3  = (const float*)d_in[10];
    const float* b_b3  = (const float*)d_in[11];
    const float* l1w   = (const float*)d_in[12];
    const float* l1b   = (const float*)d_in[13];
    const float* l2w   = (const float*)d_in[14];
    const float* l2b   = (const float*)d_in[15];
    const float* sw1r  = (const float*)d_in[16];
    const float* sw1i  = (const float*)d_in[17];
    const float* sw2r  = (const float*)d_in[18];
    const float* sw2i  = (const float*)d_in[19];
    const float* skw   = (const float*)d_in[20];
    const float* skb   = (const float*)d_in[21];
    const float* p1w   = (const float*)d_in[22];
    const float* p1b   = (const float*)d_in[23];
    const float* p2w   = (const float*)d_in[24];
    const float* p2b   = (const float*)d_in[25];

    float* ws = (float*)d_ws;
    float* stats = ws;           // 2
    float* brn   = ws + 2;       // 16
    float* t0    = ws + 32;                 // 786432
    float* t1    = t0 + 786432;             // 786432
    float2* A    = (float2*)(t1 + 786432);  // 196608 float2
    float2* O    = A + 196608;              // 98304 float2
    float* spec  = (float*)(O + 98304);     // 786432 floats

    k_bn_stats<<<1, 256, 0, stream>>>(x, stats);
    k_branch<<<1, 64, 0, stream>>>(cond, bn1_g, bn1_b, b_w1, b_b1, b_w2, b_b2, b_w3, b_b3, brn);
    k_lift<<<256, 256, 0, stream>>>(x, stats, bn2_g, bn2_b, l1w, l1b, l2w, l2b, t0);

    float* tin = t0;
    float* tout = t1;
    for (int l = 0; l < 4; l++) {
        k_fwd_w<<<192, 256, 0, stream>>>(tin, A);
        k_fwd_h_mul<<<256, 384, 0, stream>>>(A, sw1r + l * 36864, sw1i + l * 36864,
                                             sw2r + l * 36864, sw2i + l * 36864, O);
        k_inv<<<192, 256, 0, stream>>>(O, spec);
        k_skip<<<256, 256, 0, stream>>>(tin, spec, skw + l * 144, skb + l * 12, tout,
                                        (l < 3) ? 1 : 0);
        float* tmp = tin; tin = tout; tout = tmp;
    }

    k_proj<<<dim3(1024, 5), 256, 0, stream>>>(tin, p1w, p1b, p2w, p2b, brn, (float*)d_out);
}

// Round 2
// 810.884 us; speedup vs baseline: 1.4437x; 1.4437x over previous
//
#include <hip/hip_runtime.h>
#include <math.h>

#define BB 16
#define PIX 4096      // 64*64
#define NPIX 65536    // B*H*W
#define HID 12
#define LIFT 256
#define OUT_CH 640
#define EPS 1e-5f

typedef _Float16 half8 __attribute__((ext_vector_type(8)));
typedef float floatx16 __attribute__((ext_vector_type(16)));

__device__ __forceinline__ float gelu_f(float x) {
    return 0.5f * x * (1.0f + erff(x * 0.70710678118654752f));
}

// ---------------- BN2d stats over all of x ----------------
__global__ __launch_bounds__(256) void k_bn_stats(const float* __restrict__ x,
                                                  float* __restrict__ stats) {
    __shared__ float s1[256], s2[256];
    float a = 0.f, b = 0.f;
    for (int i = threadIdx.x; i < NPIX; i += 256) { float v = x[i]; a += v; b += v * v; }
    s1[threadIdx.x] = a; s2[threadIdx.x] = b;
    __syncthreads();
    for (int off = 128; off > 0; off >>= 1) {
        if (threadIdx.x < off) { s1[threadIdx.x] += s1[threadIdx.x + off];
                                 s2[threadIdx.x] += s2[threadIdx.x + off]; }
        __syncthreads();
    }
    if (threadIdx.x == 0) {
        float m = s1[0] / (float)NPIX;
        float var = s2[0] / (float)NPIX - m * m;
        stats[0] = m;
        stats[1] = rsqrtf(var + EPS);
    }
}

// ---------------- condition BN1d + branch MLP ----------------
__global__ __launch_bounds__(64) void k_branch(const float* __restrict__ cond,
                                               const float* __restrict__ g1, const float* __restrict__ b1,
                                               const float* __restrict__ w1, const float* __restrict__ bb1,
                                               const float* __restrict__ w2, const float* __restrict__ bb2,
                                               const float* __restrict__ w3, const float* __restrict__ bb3,
                                               float* __restrict__ br_out) {
    __shared__ float cm[2], cistd[2];
    int t = threadIdx.x;
    if (t < 2) {
        float s = 0.f;
        for (int i = 0; i < 16; i++) s += cond[i * 2 + t];
        float m = s / 16.f;
        float v = 0.f;
        for (int i = 0; i < 16; i++) { float d = cond[i * 2 + t] - m; v += d * d; }
        v /= 16.f;
        cm[t] = m; cistd[t] = rsqrtf(v + EPS);
    }
    __syncthreads();
    if (t < 16) {
        float c0 = (cond[t * 2 + 0] - cm[0]) * cistd[0] * g1[0] + b1[0];
        float c1 = (cond[t * 2 + 1] - cm[1]) * cistd[1] * g1[1] + b1[1];
        float h1[50], h2[50];
        for (int j = 0; j < 50; j++) h1[j] = tanhf(bb1[j] + c0 * w1[j] + c1 * w1[50 + j]);
        for (int j = 0; j < 50; j++) {
            float acc = bb2[j];
            for (int k = 0; k < 50; k++) acc += h1[k] * w2[k * 50 + j];
            h2[j] = tanhf(acc);
        }
        float acc = bb3[0];
        for (int k = 0; k < 50; k++) acc += h2[k] * w3[k];
        br_out[t] = tanhf(acc);
    }
}

// ---------------- lifting: xn -> gelu(xn*l1w+l1b) -> l2w ----------------
__global__ __launch_bounds__(256) void k_lift(const float* __restrict__ x, const float* __restrict__ stats,
                                              const float* __restrict__ g2, const float* __restrict__ b2,
                                              const float* __restrict__ l1w, const float* __restrict__ l1b,
                                              const float* __restrict__ l2w, const float* __restrict__ l2b,
                                              float* __restrict__ t0) {
    int p = blockIdx.x * 256 + threadIdx.x;
    float m = stats[0], istd = stats[1];
    float xn = (x[p] - m) * istd * g2[0] + b2[0];
    float acc[HID];
#pragma unroll
    for (int e = 0; e < HID; e++) acc[e] = l2b[e];
    for (int d = 0; d < LIFT; d++) {
        float g = gelu_f(xn * l1w[d] + l1b[d]);
#pragma unroll
        for (int e = 0; e < HID; e++) acc[e] += g * l2w[d * HID + e];
    }
    int b = p >> 12, px = p & 4095;
#pragma unroll
    for (int e = 0; e < HID; e++) t0[(b * HID + e) * PIX + px] = acc[e];
}

// ---------------- forward DFT along w (64 -> 16 modes) ----------------
__global__ __launch_bounds__(256) void k_fwd_w(const float* __restrict__ tin, float2* __restrict__ A) {
    __shared__ float tl[64 * 65];
    __shared__ float ct[64], st[64];
    int bc = blockIdx.x;  // b*12+c
    int tid = threadIdx.x;
    if (tid < 64) { float s, c; sincospif(tid * (1.0f / 32.0f), &s, &c); ct[tid] = c; st[tid] = s; }
    const float* src = tin + bc * PIX;
    for (int i = tid; i < PIX; i += 256) {
        int h = i >> 6, w = i & 63;
        tl[h * 65 + w] = src[i];
    }
    __syncthreads();
    for (int o = tid; o < 1024; o += 256) {
        int kw = o >> 6, h = o & 63;
        float xr = 0.f, xi = 0.f;
        for (int w = 0; w < 64; w++) {
            int j = (kw * w) & 63;
            float v = tl[h * 65 + w];
            xr += v * ct[j];
            xi -= v * st[j];
        }
        A[(bc * 16 + kw) * 64 + h] = make_float2(xr, xi);
    }
}

// ---------------- forward DFT along h (64 -> 32 rows) + spectral multiply ----------------
__global__ __launch_bounds__(384) void k_fwd_h_mul(const float2* __restrict__ A,
                                                   const float* __restrict__ w1r, const float* __restrict__ w1i,
                                                   const float* __restrict__ w2r, const float* __restrict__ w2i,
                                                   float2* __restrict__ O) {
    __shared__ float2 Al[12 * 64];
    __shared__ float2 Xl[12 * 32];
    __shared__ float ct[64], st[64];
    int b = blockIdx.x >> 4;
    int kw = blockIdx.x & 15;
    int tid = threadIdx.x;
    if (tid < 64) { float s, c; sincospif(tid * (1.0f / 32.0f), &s, &c); ct[tid] = c; st[tid] = s; }
    for (int i = tid; i < 12 * 64; i += 384) {
        int c = i >> 6, h = i & 63;
        Al[i] = A[((b * 12 + c) * 16 + kw) * 64 + h];
    }
    __syncthreads();
    {
        int c = tid >> 5, kh = tid & 31;
        int f = (kh < 16) ? kh : kh + 32;
        float xr = 0.f, xi = 0.f;
        for (int h = 0; h < 64; h++) {
            int j = (f * h) & 63;
            float2 a = Al[c * 64 + h];
            float cc = ct[j], ss = st[j];
            xr += a.x * cc + a.y * ss;
            xi += a.y * cc - a.x * ss;
        }
        Xl[c * 32 + kh] = make_float2(xr, xi);
    }
    __syncthreads();
    {
        int o = tid >> 5, kh = tid & 31;
        int khr = kh & 15;
        const float* wr = (kh < 16) ? w1r : w2r;
        const float* wi = (kh < 16) ? w1i : w2i;
        float orr = 0.f, oii = 0.f;
        for (int c = 0; c < 12; c++) {
            float2 xv = Xl[c * 32 + kh];
            int wIdx = ((c * 12 + o) * 16 + khr) * 16 + kw;
            float wrv = wr[wIdx], wiv = wi[wIdx];
            orr += xv.x * wrv - xv.y * wiv;
            oii += xv.x * wiv + xv.y * wrv;
        }
        O[((b * 12 + o) * 32 + kh) * 16 + kw] = make_float2(orr, oii);
    }
}

// ---------------- inverse DFTs ----------------
__global__ __launch_bounds__(256) void k_inv(const float2* __restrict__ O, float* __restrict__ spec) {
    __shared__ float2 Ol[32 * 16];
    __shared__ float2 Yl[64 * 17];
    __shared__ float ct[64], st[64];
    int bo = blockIdx.x;
    int tid = threadIdx.x;
    if (tid < 64) { float s, c; sincospif(tid * (1.0f / 32.0f), &s, &c); ct[tid] = c; st[tid] = s; }
    for (int i = tid; i < 512; i += 256) Ol[i] = O[bo * 512 + i];
    __syncthreads();
    for (int oidx = tid; oidx < 1024; oidx += 256) {
        int kw = oidx >> 6, h = oidx & 63;
        float yr = 0.f, yi = 0.f;
        for (int kh = 0; kh < 32; kh++) {
            int f = (kh < 16) ? kh : kh + 32;
            int j = (f * h) & 63;
            float2 ov = Ol[kh * 16 + kw];
            float cc = ct[j], ss = st[j];
            yr += ov.x * cc - ov.y * ss;
            yi += ov.x * ss + ov.y * cc;
        }
        Yl[h * 17 + kw] = make_float2(yr * (1.0f / 4096.0f), yi * (1.0f / 4096.0f));
    }
    __syncthreads();
    for (int i = tid; i < PIX; i += 256) {
        int h = i >> 6, w = i & 63;
        float acc = 0.f;
#pragma unroll
        for (int kw = 0; kw < 16; kw++) {
            int j = (kw * w) & 63;
            float2 yv = Yl[h * 17 + kw];
            float term = yv.x * ct[j] - yv.y * st[j];
            acc += (kw == 0) ? term : 2.0f * term;
        }
        spec[bo * PIX + i] = acc;
    }
}

// ---------------- spec + 1x1-conv skip + (gelu) ----------------
__global__ __launch_bounds__(256) void k_skip(const float* __restrict__ tin, const float* __restrict__ spec,
                                              const float* __restrict__ skw, const float* __restrict__ skb,
                                              float* __restrict__ tout, int apply_gelu) {
    int p = blockIdx.x * 256 + threadIdx.x;
    int b = p >> 12, px = p & 4095;
    float tr[12];
#pragma unroll
    for (int c = 0; c < 12; c++) tr[c] = tin[(b * 12 + c) * PIX + px];
#pragma unroll
    for (int o = 0; o < 12; o++) {
        float v = spec[(b * 12 + o) * PIX + px] + skb[o];
#pragma unroll
        for (int c = 0; c < 12; c++) v += tr[c] * skw[c * 12 + o];
        if (apply_gelu) v = gelu_f(v);
        tout[(b * 12 + o) * PIX + px] = v;
    }
}

// ---------------- p2w [256][640] fp32 -> fragment-ordered fp16 ----------------
// layout (halfs): eg*8192 + ks*512 + kh*256 + (e&31)*8 + j  ;  k = ks*16+kh*8+j
__global__ __launch_bounds__(256) void k_wt(const float* __restrict__ p2w, _Float16* __restrict__ wt) {
    int eg = blockIdx.x;  // 20 groups of 32 e
    int tid = threadIdx.x;
    for (int idx = tid; idx < 1024; idx += 256) {
        int m = idx & 31, kh = (idx >> 5) & 1, ks = idx >> 6;
        half8 v;
#pragma unroll
        for (int j = 0; j < 8; j++)
            v[j] = (_Float16)p2w[(ks * 16 + kh * 8 + j) * 640 + eg * 32 + m];
        *(half8*)&wt[eg * 8192 + ks * 512 + kh * 256 + m * 8] = v;
    }
}

// ---------------- projection via fp16 MFMA ----------------
// grid (512 px-blocks of 128, 5 e-blocks of 128), 256 threads = 4 waves
// wave (we,wp) computes 64e x 64px as 2x2 tiles of 32x32 (m=e rows, n=px cols)
__global__ __launch_bounds__(256, 2) void k_proj_mfma(const float* __restrict__ t,
                                                      const float* __restrict__ p1w,
                                                      const float* __restrict__ p1b,
                                                      const _Float16* __restrict__ wt,
                                                      const float* __restrict__ p2b,
                                                      const float* __restrict__ brn,
                                                      float* __restrict__ out) {
    __shared__ __align__(16) _Float16 ql[128 * 256];  // 64 KB, fragment order
    int pxb = blockIdx.x * 128;
    int eb  = blockIdx.y * 128;
    int tid = threadIdx.x;

    // phase A: q = gelu(t . p1w + p1b), fp16 into LDS fragment layout
    {
        int pxl = tid & 127;
        int dg  = tid >> 7;       // d-range dg*128 .. dg*128+127
        int px  = pxb + pxl;
        int b = px >> 12, pimg = px & 4095;
        float tv[12];
#pragma unroll
        for (int c = 0; c < 12; c++) tv[c] = t[(b * 12 + c) * PIX + pimg];
        int pg = pxl >> 5, pm = pxl & 31;
        for (int dd = 0; dd < 128; dd += 8) {
            half8 hv;
#pragma unroll
            for (int i = 0; i < 8; i++) {
                int d = dg * 128 + dd + i;
                float a = p1b[d];
#pragma unroll
                for (int c = 0; c < 12; c++) a += tv[c] * p1w[c * 256 + d];
                hv[i] = (_Float16)gelu_f(a);
            }
            int d0 = dg * 128 + dd;
            int ks = d0 >> 4, kh = (d0 >> 3) & 1;
            *(half8*)&ql[pg * 8192 + ks * 512 + kh * 256 + pm * 8] = hv;
        }
    }
    __syncthreads();

    // phase B: MFMA GEMM
    int wave = tid >> 6, lane = tid & 63;
    int we = wave >> 1, wp = wave & 1;
    int lo = (lane >> 5) * 256 + (lane & 31) * 8;  // frag offset in halfs
    int eg0 = (eb + we * 64) >> 5;                 // global e-group (32-wide)
    int pg0 = wp * 2;                              // local px-group

    floatx16 acc[2][2];
#pragma unroll
    for (int a = 0; a < 2; a++)
#pragma unroll
        for (int b2 = 0; b2 < 2; b2++)
#pragma unroll
            for (int i = 0; i < 16; i++) acc[a][b2][i] = 0.f;

#pragma unroll
    for (int ks = 0; ks < 16; ks++) {
        half8 a0 = *(const half8*)(wt + eg0 * 8192 + ks * 512 + lo);
        half8 a1 = *(const half8*)(wt + (eg0 + 1) * 8192 + ks * 512 + lo);
        half8 b0 = *(const half8*)&ql[pg0 * 8192 + ks * 512 + lo];
        half8 b1 = *(const half8*)&ql[(pg0 + 1) * 8192 + ks * 512 + lo];
        acc[0][0] = __builtin_amdgcn_mfma_f32_32x32x16_f16(a0, b0, acc[0][0], 0, 0, 0);
        acc[0][1] = __builtin_amdgcn_mfma_f32_32x32x16_f16(a0, b1, acc[0][1], 0, 0, 0);
        acc[1][0] = __builtin_amdgcn_mfma_f32_32x32x16_f16(a1, b0, acc[1][0], 0, 0, 0);
        acc[1][1] = __builtin_amdgcn_mfma_f32_32x32x16_f16(a1, b1, acc[1][1], 0, 0, 0);
    }

    // epilogue: D row = e, col = px; out[b][h][e][w]
    float brv = brn[pxb >> 12];
#pragma unroll
    for (int ta = 0; ta < 2; ta++) {
#pragma unroll
        for (int tb = 0; tb < 2; tb++) {
            int e_base = eb + we * 64 + ta * 32;
            int px = pxb + wp * 64 + tb * 32 + (lane & 31);
            int bh = px >> 6, w = px & 63;
            float* op = out + bh * 640 * 64 + w;
#pragma unroll
            for (int r = 0; r < 16; r++) {
                int row = (r & 3) + 8 * (r >> 2) + 4 * (lane >> 5);
                int e = e_base + row;
                op[e * 64] = (acc[ta][tb][r] + p2b[e]) * brv;
            }
        }
    }
}

extern "C" void kernel_launch(void* const* d_in, const int* in_sizes, int n_in,
                              void* d_out, int out_size, void* d_ws, size_t ws_size,
                              hipStream_t stream) {
    const float* x     = (const float*)d_in[0];
    const float* cond  = (const float*)d_in[1];
    const float* bn2_g = (const float*)d_in[2];
    const float* bn2_b = (const float*)d_in[3];
    const float* bn1_g = (const float*)d_in[4];
    const float* bn1_b = (const float*)d_in[5];
    const float* b_w1  = (const float*)d_in[6];
    const float* b_b1  = (const float*)d_in[7];
    const float* b_w2  = (const float*)d_in[8];
    const float* b_b2  = (const float*)d_in[9];
    const float* b_w3  = (const float*)d_in[10];
    const float* b_b3  = (const float*)d_in[11];
    const float* l1w   = (const float*)d_in[12];
    const float* l1b   = (const float*)d_in[13];
    const float* l2w   = (const float*)d_in[14];
    const float* l2b   = (const float*)d_in[15];
    const float* sw1r  = (const float*)d_in[16];
    const float* sw1i  = (const float*)d_in[17];
    const float* sw2r  = (const float*)d_in[18];
    const float* sw2i  = (const float*)d_in[19];
    const float* skw   = (const float*)d_in[20];
    const float* skb   = (const float*)d_in[21];
    const float* p1w   = (const float*)d_in[22];
    const float* p1b   = (const float*)d_in[23];
    const float* p2w   = (const float*)d_in[24];
    const float* p2b   = (const float*)d_in[25];

    float* ws = (float*)d_ws;
    float* stats = ws;                      // 2
    float* brn   = ws + 2;                  // 16
    float* t0    = ws + 32;                 // 786432
    float* t1    = t0 + 786432;             // 786432
    float2* A    = (float2*)(t1 + 786432);  // 196608 float2
    float2* O    = A + 196608;              // 98304 float2
    float* spec  = (float*)(O + 98304);     // 786432 floats
    _Float16* wt = (_Float16*)(spec + 786432);  // 163840 halfs

    k_bn_stats<<<1, 256, 0, stream>>>(x, stats);
    k_branch<<<1, 64, 0, stream>>>(cond, bn1_g, bn1_b, b_w1, b_b1, b_w2, b_b2, b_w3, b_b3, brn);
    k_lift<<<256, 256, 0, stream>>>(x, stats, bn2_g, bn2_b, l1w, l1b, l2w, l2b, t0);
    k_wt<<<20, 256, 0, stream>>>(p2w, wt);

    float* tin = t0;
    float* tout = t1;
    for (int l = 0; l < 4; l++) {
        k_fwd_w<<<192, 256, 0, stream>>>(tin, A);
        k_fwd_h_mul<<<256, 384, 0, stream>>>(A, sw1r + l * 36864, sw1i + l * 36864,
                                             sw2r + l * 36864, sw2i + l * 36864, O);
        k_inv<<<192, 256, 0, stream>>>(O, spec);
        k_skip<<<256, 256, 0, stream>>>(tin, spec, skw + l * 144, skb + l * 12, tout,
                                        (l < 3) ? 1 : 0);
        float* tmp = tin; tin = tout; tout = tmp;
    }

    k_proj_mfma<<<dim3(512, 5), 256, 0, stream>>>(tin, p1w, p1b, wt, p2b, brn, (float*)d_out);
}